// Round 1
// baseline (1101.420 us; speedup 1.0000x reference)
//
#include <hip/hip_runtime.h>

#define BB 4
#define HH 8
#define NN 4096
#define DD 64
#define RR 256

constexpr float SCALE = 0.35355339059327373f;  // 64^(-1/4)
constexpr float KEPS  = 0.001f;

// ---------------------------------------------------------------------------
// Pass 1: per (b,h) compute ctx[r][d] = sum_n phi_k[n][r] * V[n][d] * m[n]
//         and ksum[r] = sum_n phi_k[n][r],  phi_k = relu(m*scale*(K[n]·proj[r]))+eps
// grid (NN/ROWS1, HH, BB), block 256 (thread == r). ctx row kept in registers,
// K/V rows staged in LDS tiles (broadcast reads), atomicAdd finish.
// ---------------------------------------------------------------------------
#define ROWS1 512
#define TILE1 32

__global__ __launch_bounds__(256, 2)
void performer_pass1(const float* __restrict__ Kmat, const float* __restrict__ Vmat,
                     const float* __restrict__ mask, const float* __restrict__ proj,
                     float* __restrict__ g_ctx, float* __restrict__ g_ksum)
{
    const int r  = threadIdx.x;
    const int b  = blockIdx.z, h = blockIdx.y;
    const int bh = b * HH + h;
    const int n0 = blockIdx.x * ROWS1;
    const long base = ((long)bh * NN + n0) * DD;

    __shared__ float klds[TILE1][DD];   // 8 KB
    __shared__ float vlds[TILE1][DD];   // 8 KB
    __shared__ float mlds[TILE1];

    // proj row r -> registers
    float pr[DD];
#pragma unroll
    for (int d = 0; d < DD; d += 4) {
        const float4 t = *(const float4*)(proj + r * DD + d);
        pr[d] = t.x; pr[d+1] = t.y; pr[d+2] = t.z; pr[d+3] = t.w;
    }
    float ctx[DD];
#pragma unroll
    for (int d = 0; d < DD; ++d) ctx[d] = 0.f;
    float ksum = 0.f;

    for (int t0 = 0; t0 < ROWS1; t0 += TILE1) {
        __syncthreads();
        // stage TILE1 rows of K and V (TILE1*DD = 2048 floats each, contiguous)
        for (int i = r * 4; i < TILE1 * DD; i += 256 * 4) {
            *(float4*)(&klds[0][0] + i) = *(const float4*)(Kmat + base + (long)t0 * DD + i);
            *(float4*)(&vlds[0][0] + i) = *(const float4*)(Vmat + base + (long)t0 * DD + i);
        }
        if (r < TILE1) mlds[r] = mask[b * NN + n0 + t0 + r];
        __syncthreads();

#pragma unroll 2
        for (int i = 0; i < TILE1; ++i) {
            float d0 = 0.f, d1 = 0.f, d2 = 0.f, d3 = 0.f;
#pragma unroll
            for (int d = 0; d < DD; d += 4) {
                d0 = fmaf(klds[i][d],   pr[d],   d0);
                d1 = fmaf(klds[i][d+1], pr[d+1], d1);
                d2 = fmaf(klds[i][d+2], pr[d+2], d2);
                d3 = fmaf(klds[i][d+3], pr[d+3], d3);
            }
            const float m   = mlds[i];
            const float dot = (d0 + d1) + (d2 + d3);
            const float phi = fmaxf(dot * (SCALE * m), 0.f) + KEPS;  // phi_k
            ksum += phi;
            const float pm = phi * m;                                // phi_k * mask (for V)
#pragma unroll
            for (int d = 0; d < DD; ++d)
                ctx[d] = fmaf(pm, vlds[i][d], ctx[d]);
        }
    }

    float* dst = g_ctx + ((long)bh * RR + r) * DD;
#pragma unroll
    for (int d = 0; d < DD; ++d) atomicAdd(dst + d, ctx[d]);
    atomicAdd(g_ksum + bh * RR + r, ksum);
}

// ---------------------------------------------------------------------------
// Pass 2: per row n: phi_q[r] = relu(scale*Q[n]·proj[r])+eps;
//         s = phi_q·ksum; out[n][d] = (1/s) * sum_r phi_q[r]*ctx[r][d]
// grid (NN/256, HH, BB), block 256 (thread == n). proj/ctx staged in LDS in
// 64-row stages (uniform broadcast reads); q row + out accumulator in regs.
// ---------------------------------------------------------------------------
#define RTILE 64

__global__ __launch_bounds__(256, 2)
void performer_pass2(const float* __restrict__ Qmat, const float* __restrict__ proj,
                     const float* __restrict__ g_ctx, const float* __restrict__ g_ksum,
                     float* __restrict__ out)
{
    const int tid = threadIdx.x;
    const int b = blockIdx.z, h = blockIdx.y;
    const int bh = b * HH + h;
    const int n  = blockIdx.x * 256 + tid;

    __shared__ float ph[RTILE][DD];       // 16 KB
    __shared__ float ch[RTILE][DD + 4];   // 17 KB; col DD holds ksum, +4 keeps 16B align

    float qv[DD];
    {
        const float* qp = Qmat + ((long)bh * NN + n) * DD;
#pragma unroll
        for (int d = 0; d < DD; d += 4) {
            const float4 t = *(const float4*)(qp + d);
            qv[d] = t.x * SCALE; qv[d+1] = t.y * SCALE;
            qv[d+2] = t.z * SCALE; qv[d+3] = t.w * SCALE;
        }
    }
    float oacc[DD];
#pragma unroll
    for (int d = 0; d < DD; ++d) oacc[d] = 0.f;
    float s = 0.f;

    for (int r0 = 0; r0 < RR; r0 += RTILE) {
        __syncthreads();
        for (int i = tid * 4; i < RTILE * DD; i += 256 * 4) {
            const int row = i >> 6, col = i & 63;
            *(float4*)&ph[row][col] = *(const float4*)(proj + (long)(r0 + row) * DD + col);
            *(float4*)&ch[row][col] = *(const float4*)(g_ctx + ((long)bh * RR + r0 + row) * DD + col);
        }
        if (tid < RTILE) ch[tid][DD] = g_ksum[bh * RR + r0 + tid];
        __syncthreads();

#pragma unroll 2
        for (int rl = 0; rl < RTILE; ++rl) {
            float d0 = 0.f, d1 = 0.f, d2 = 0.f, d3 = 0.f;
#pragma unroll
            for (int d = 0; d < DD; d += 4) {
                d0 = fmaf(ph[rl][d],   qv[d],   d0);
                d1 = fmaf(ph[rl][d+1], qv[d+1], d1);
                d2 = fmaf(ph[rl][d+2], qv[d+2], d2);
                d3 = fmaf(ph[rl][d+3], qv[d+3], d3);
            }
            const float phi = fmaxf((d0 + d1) + (d2 + d3), 0.f) + KEPS;  // phi_q
            s = fmaf(phi, ch[rl][DD], s);
#pragma unroll
            for (int d = 0; d < DD; ++d)
                oacc[d] = fmaf(phi, ch[rl][d], oacc[d]);
        }
    }

    const float dinv = 1.0f / s;
    float* op = out + ((long)bh * NN + n) * DD;
#pragma unroll
    for (int d = 0; d < DD; d += 4) {
        float4 t;
        t.x = oacc[d] * dinv; t.y = oacc[d+1] * dinv;
        t.z = oacc[d+2] * dinv; t.w = oacc[d+3] * dinv;
        *(float4*)(op + d) = t;
    }
}

// ---------------------------------------------------------------------------
extern "C" void kernel_launch(void* const* d_in, const int* in_sizes, int n_in,
                              void* d_out, int out_size, void* d_ws, size_t ws_size,
                              hipStream_t stream)
{
    const float* Q    = (const float*)d_in[0];
    const float* K    = (const float*)d_in[1];
    const float* V    = (const float*)d_in[2];
    const float* mask = (const float*)d_in[3];
    const float* proj = (const float*)d_in[4];
    float* out = (float*)d_out;

    float* g_ctx  = (float*)d_ws;                      // BB*HH*RR*DD floats (2 MB)
    float* g_ksum = g_ctx + (size_t)BB * HH * RR * DD; // BB*HH*RR floats (32 KB)
    const size_t zbytes = ((size_t)BB * HH * RR * DD + (size_t)BB * HH * RR) * sizeof(float);
    hipMemsetAsync(d_ws, 0, zbytes, stream);

    dim3 g1(NN / ROWS1, HH, BB);   // (8, 8, 4) = 256 blocks
    performer_pass1<<<g1, 256, 0, stream>>>(K, V, mask, proj, g_ctx, g_ksum);

    dim3 g2(NN / 256, HH, BB);     // (16, 8, 4) = 512 blocks
    performer_pass2<<<g2, 256, 0, stream>>>(Q, proj, g_ctx, g_ksum, out);
}

// Round 2
// 836.934 us; speedup vs baseline: 1.3160x; 1.3160x over previous
//
#include <hip/hip_runtime.h>

#define BB 4
#define HH 8
#define NN 4096
#define DD 64
#define RR 256

constexpr float SCALE = 0.35355339059327373f;  // 64^(-1/4)
constexpr float KEPS  = 0.001f;

// ---------------------------------------------------------------------------
// Pass 1: per (b,h) compute ctx[r][d] = sum_n phi_k[n][r] * V[n][d] * m[n]
//         and ksum[r] = sum_n phi_k[n][r]
// grid (NN/ROWS1=32, HH, BB) = 1024 blocks (4/CU -> 16 waves/CU), block 256
// (thread == r). ctx row in registers; K/V tiles in LDS (broadcast reads);
// epilogue: LDS-transposed COALESCED atomicAdd (lane-consecutive addresses).
// ---------------------------------------------------------------------------
#define ROWS1 128
#define TILE1 32

__global__ __launch_bounds__(256, 2)
void performer_pass1(const float* __restrict__ Kmat, const float* __restrict__ Vmat,
                     const float* __restrict__ mask, const float* __restrict__ proj,
                     float* __restrict__ g_ctx, float* __restrict__ g_ksum)
{
    const int r  = threadIdx.x;
    const int b  = blockIdx.z, h = blockIdx.y;
    const int bh = b * HH + h;
    const int n0 = blockIdx.x * ROWS1;
    const long base = ((long)bh * NN + n0) * DD;

    __shared__ float klds[TILE1][DD];      // 8 KB
    __shared__ float vlds[TILE1][DD];      // 8 KB
    __shared__ float mlds[TILE1];
    __shared__ float ep[DD][33];           // 8.25 KB transposed epilogue staging

    float pr[DD];
#pragma unroll
    for (int d = 0; d < DD; d += 4) {
        const float4 t = *(const float4*)(proj + r * DD + d);
        pr[d] = t.x; pr[d+1] = t.y; pr[d+2] = t.z; pr[d+3] = t.w;
    }
    float ctx[DD];
#pragma unroll
    for (int d = 0; d < DD; ++d) ctx[d] = 0.f;
    float ksum = 0.f;

    for (int t0 = 0; t0 < ROWS1; t0 += TILE1) {
        __syncthreads();
        for (int i = r * 4; i < TILE1 * DD; i += 256 * 4) {
            *(float4*)(&klds[0][0] + i) = *(const float4*)(Kmat + base + (long)t0 * DD + i);
            *(float4*)(&vlds[0][0] + i) = *(const float4*)(Vmat + base + (long)t0 * DD + i);
        }
        if (r < TILE1) mlds[r] = mask[b * NN + n0 + t0 + r];
        __syncthreads();

#pragma unroll 2
        for (int i = 0; i < TILE1; ++i) {
            float d0 = 0.f, d1 = 0.f, d2 = 0.f, d3 = 0.f;
#pragma unroll
            for (int d = 0; d < DD; d += 4) {
                d0 = fmaf(klds[i][d],   pr[d],   d0);
                d1 = fmaf(klds[i][d+1], pr[d+1], d1);
                d2 = fmaf(klds[i][d+2], pr[d+2], d2);
                d3 = fmaf(klds[i][d+3], pr[d+3], d3);
            }
            const float m   = mlds[i];
            const float dot = (d0 + d1) + (d2 + d3);
            const float phi = fmaxf(dot * (SCALE * m), 0.f) + KEPS;
            ksum += phi;
            const float pm = phi * m;
#pragma unroll
            for (int d = 0; d < DD; ++d)
                ctx[d] = fmaf(pm, vlds[i][d], ctx[d]);
        }
    }

    // ksum: r == tid -> already lane-consecutive, coalesced atomics
    atomicAdd(g_ksum + bh * RR + r, ksum);

    // ctx epilogue: 8 chunks of 32 r-rows, transposed through LDS so the
    // atomicAdd addresses are lane-consecutive (4 lines/wave, not 64).
    for (int c = 0; c < 8; ++c) {
        __syncthreads();
        if ((r >> 5) == c) {
            const int row = r & 31;
#pragma unroll
            for (int d = 0; d < DD; ++d) ep[d][row] = ctx[d];  // banks = (33d+row)%32: conflict-free
        }
        __syncthreads();
        const long gbase = ((long)bh * RR + c * 32) * DD;
#pragma unroll
        for (int k = 0; k < 8; ++k) {
            const int g = r + k * 256;            // flat idx in 32x64 chunk = row*64+d
            const float v = ep[g & 63][g >> 6];   // stride-33 reads: conflict-free
            atomicAdd(g_ctx + gbase + g, v);
        }
    }
}

// ---------------------------------------------------------------------------
// Pass 2: out_acc[n][d] += sum_{r in half} phi_q[n][r]*ctx[r][d],
//         s_buf[n] += sum_{r in half} phi_q[n][r]*ksum[r]
// grid (16*2, HH, BB) = 1024 blocks (16 waves/CU); blockIdx.x = nchunk*2+rhalf.
// ---------------------------------------------------------------------------
#define RTILE 64
#define CH_STRIDE (DD + 4)

__global__ __launch_bounds__(256, 2)
void performer_pass2(const float* __restrict__ Qmat, const float* __restrict__ proj,
                     const float* __restrict__ g_ctx, const float* __restrict__ g_ksum,
                     float* __restrict__ s_buf, float* __restrict__ out_acc)
{
    const int tid = threadIdx.x;
    const int b = blockIdx.z, h = blockIdx.y;
    const int bh = b * HH + h;
    const int nchunk = blockIdx.x >> 1;
    const int rbase  = (blockIdx.x & 1) * 128;
    const int n = nchunk * 256 + tid;

    __shared__ float ph[RTILE][DD];          // 16 KB
    __shared__ float ch[RTILE][CH_STRIDE];   // 17 KB; col DD holds ksum

    float qv[DD];
    {
        const float* qp = Qmat + ((long)bh * NN + n) * DD;
#pragma unroll
        for (int d = 0; d < DD; d += 4) {
            const float4 t = *(const float4*)(qp + d);
            qv[d] = t.x * SCALE; qv[d+1] = t.y * SCALE;
            qv[d+2] = t.z * SCALE; qv[d+3] = t.w * SCALE;
        }
    }
    float oacc[DD];
#pragma unroll
    for (int d = 0; d < DD; ++d) oacc[d] = 0.f;
    float s = 0.f;

    for (int r0 = rbase; r0 < rbase + 128; r0 += RTILE) {
        __syncthreads();
        for (int i = tid * 4; i < RTILE * DD; i += 256 * 4) {
            const int row = i >> 6, col = i & 63;
            *(float4*)&ph[row][col] = *(const float4*)(proj + (long)(r0 + row) * DD + col);
            *(float4*)&ch[row][col] = *(const float4*)(g_ctx + ((long)bh * RR + r0 + row) * DD + col);
        }
        if (tid < RTILE) ch[tid][DD] = g_ksum[bh * RR + r0 + tid];
        __syncthreads();

#pragma unroll 2
        for (int rl = 0; rl < RTILE; ++rl) {
            float d0 = 0.f, d1 = 0.f, d2 = 0.f, d3 = 0.f;
#pragma unroll
            for (int d = 0; d < DD; d += 4) {
                d0 = fmaf(ph[rl][d],   qv[d],   d0);
                d1 = fmaf(ph[rl][d+1], qv[d+1], d1);
                d2 = fmaf(ph[rl][d+2], qv[d+2], d2);
                d3 = fmaf(ph[rl][d+3], qv[d+3], d3);
            }
            const float phi = fmaxf((d0 + d1) + (d2 + d3), 0.f) + KEPS;
            s = fmaf(phi, ch[rl][DD], s);
#pragma unroll
            for (int d = 0; d < DD; ++d)
                oacc[d] = fmaf(phi, ch[rl][d], oacc[d]);
        }
    }

    atomicAdd(s_buf + bh * NN + n, s);   // lane-consecutive

    // out epilogue: 4 chunks of 64 n-rows staged through ch (stride 68),
    // then coalesced atomicAdd.
    for (int c = 0; c < 4; ++c) {
        __syncthreads();
        if ((tid >> 6) == c) {
            const int row = tid & 63;
#pragma unroll
            for (int d = 0; d < DD; d += 4)
                *(float4*)&ch[row][d] = *(const float4*)&oacc[d];
        }
        __syncthreads();
        const long gbase = ((long)bh * NN + nchunk * 256 + c * 64) * DD;
#pragma unroll
        for (int k = 0; k < 16; ++k) {
            const int g = tid + k * 256;          // flat idx in 64x64 chunk
            const float v = ch[g >> 6][g & 63];   // same row per wave: conflict-free
            atomicAdd(out_acc + gbase + g, v);
        }
    }
}

// ---------------------------------------------------------------------------
// Pass 3: out[n][d] *= 1/s[n]
// ---------------------------------------------------------------------------
__global__ __launch_bounds__(256)
void performer_norm(float* __restrict__ out, const float* __restrict__ s_buf)
{
    const long i = (long)blockIdx.x * 256 + threadIdx.x;  // float4 index
    const int row = (int)(i >> 4);                        // 16 float4 per row
    float4 v = ((float4*)out)[i];
    const float inv = 1.0f / s_buf[row];
    v.x *= inv; v.y *= inv; v.z *= inv; v.w *= inv;
    ((float4*)out)[i] = v;
}

// ---------------------------------------------------------------------------
extern "C" void kernel_launch(void* const* d_in, const int* in_sizes, int n_in,
                              void* d_out, int out_size, void* d_ws, size_t ws_size,
                              hipStream_t stream)
{
    const float* Q    = (const float*)d_in[0];
    const float* K    = (const float*)d_in[1];
    const float* V    = (const float*)d_in[2];
    const float* mask = (const float*)d_in[3];
    const float* proj = (const float*)d_in[4];
    float* out = (float*)d_out;

    float* g_ctx  = (float*)d_ws;                        // BH*RR*DD floats (2 MB)
    float* g_ksum = g_ctx  + (size_t)BB * HH * RR * DD;  // BH*RR floats
    float* s_buf  = g_ksum + (size_t)BB * HH * RR;       // BH*NN floats (512 KB)
    const size_t zfloats = (size_t)BB * HH * (RR * DD + RR + NN);
    hipMemsetAsync(d_ws, 0, zfloats * sizeof(float), stream);
    hipMemsetAsync(d_out, 0, (size_t)out_size * sizeof(float), stream);

    dim3 g1(NN / ROWS1, HH, BB);   // (32, 8, 4) = 1024 blocks
    performer_pass1<<<g1, 256, 0, stream>>>(K, V, mask, proj, g_ctx, g_ksum);

    dim3 g2((NN / 256) * 2, HH, BB);  // (32, 8, 4) = 1024 blocks
    performer_pass2<<<g2, 256, 0, stream>>>(Q, proj, g_ctx, g_ksum, s_buf, out);

    const long nvec4 = (long)BB * HH * NN * DD / 4;
    performer_norm<<<nvec4 / 256, 256, 0, stream>>>(out, s_buf);
}

// Round 3
// 196.861 us; speedup vs baseline: 5.5949x; 4.2514x over previous
//
#include <hip/hip_runtime.h>

#define BB 4
#define HH 8
#define NN 4096
#define DD 64
#define RR 256

constexpr float SCALE = 0.35355339059327373f;  // 64^(-1/4)
constexpr float KEPS  = 0.001f;

typedef __attribute__((ext_vector_type(8)))  short short8;   // 8 bf16 = MFMA A/B frag
typedef __attribute__((ext_vector_type(4)))  short short4v;  // 4 bf16 (b64 write)
typedef __attribute__((ext_vector_type(16))) float f32x16;   // 32x32 MFMA C/D

#define MFMA(a, b, c) __builtin_amdgcn_mfma_f32_32x32x16_bf16(a, b, c, 0, 0, 0)

__device__ inline short f2bf(float f) {            // fp32 -> bf16 RTNE
    unsigned u = __float_as_uint(f);
    return (short)((u + 0x7FFFu + ((u >> 16) & 1u)) >> 16);
}
__device__ inline float bf2f(short s) {
    return __uint_as_float(((unsigned)(unsigned short)s) << 16);
}
__device__ inline f32x16 fzero16() {
    f32x16 z;
#pragma unroll
    for (int e = 0; e < 16; ++e) z[e] = 0.f;
    return z;
}

// ---------------------------------------------------------------------------
// Kernel 1: per (bh, n-chunk of 256):
//   phi_k[n][r] = relu(scale*m[n]*(K.projT)) + eps         (MFMA, C: m=n col=r)
//   ctx[r][d]  += phi_k^T . (V*m)                          (MFMA, C: m=r col=d)
//   ksum[r]    += sum_n phi_k[n][r]                        (epilogue reduce)
// phi round-trips LDS in A-operand layout ([r][n-fastest], quad b64 writes).
// V transposed to [d][n-fastest] via LDS gather (B-operand layout).
// MFMA frag layouts (32x32x16): A[m=lane&31][k=(lane>>5)*8+j],
// B[k=(lane>>5)*8+j][col=lane&31], C row=(reg&3)+8*(reg>>2)+4*(lane>>5).
// ---------------------------------------------------------------------------
#define NT1 256

__global__ __launch_bounds__(256, 2)
void pk_ctx_kernel(const float* __restrict__ Kmat, const float* __restrict__ Vmat,
                   const float* __restrict__ mask, const float* __restrict__ proj,
                   float* __restrict__ g_ctx, float* __restrict__ g_ksum)
{
    __shared__ __align__(16) short kt[32 * 72];    // K subtile [n][d], pad 72
    __shared__ __align__(16) short vrm[32 * 72];   // V*m row-major temp
    __shared__ __align__(16) short vt[64 * 40];    // V^T [d][n], pad 40
    __shared__ __align__(16) short phiT[256 * 40]; // phi^T [r][n], pad 40
    __shared__ float mlds[32];

    const int tid  = threadIdx.x;
    const int wave = tid >> 6, lane = tid & 63;
    const int l31  = lane & 31, hf = lane >> 5;
    const int b = blockIdx.z, h = blockIdx.y;
    const int bh = b * HH + h;
    const int n0 = blockIdx.x * NT1;

    // resident proj B-frags: col r = wave*64 + rt*32 + l31, k d = ks*16+hf*8+j
    short8 pfrag[2][4];
#pragma unroll
    for (int rt = 0; rt < 2; ++rt)
#pragma unroll
        for (int ks = 0; ks < 4; ++ks) {
            const int r  = wave * 64 + rt * 32 + l31;
            const int d0 = ks * 16 + hf * 8;
            const float4 a = *(const float4*)(proj + r * DD + d0);
            const float4 c = *(const float4*)(proj + r * DD + d0 + 4);
            short8 v;
            v[0] = f2bf(a.x); v[1] = f2bf(a.y); v[2] = f2bf(a.z); v[3] = f2bf(a.w);
            v[4] = f2bf(c.x); v[5] = f2bf(c.y); v[6] = f2bf(c.z); v[7] = f2bf(c.w);
            pfrag[rt][ks] = v;
        }

    f32x16 cacc[2][2];
#pragma unroll
    for (int i = 0; i < 2; ++i)
#pragma unroll
        for (int j = 0; j < 2; ++j) cacc[i][j] = fzero16();
    float ksum_acc[2] = {0.f, 0.f};

    const int  sn = tid >> 3, sdc = tid & 7;
    const long kbase = ((long)bh * NN + n0) * DD;

    for (int sub = 0; sub < NT1 / 32; ++sub) {
        __syncthreads();
        // ---- stage K, V*m (bf16, row-major padded), mask ----
        {
            const long off = kbase + (long)sub * 32 * DD + tid * 8;
            const float4 ka = *(const float4*)(Kmat + off);
            const float4 kb = *(const float4*)(Kmat + off + 4);
            short8 kv;
            kv[0] = f2bf(ka.x); kv[1] = f2bf(ka.y); kv[2] = f2bf(ka.z); kv[3] = f2bf(ka.w);
            kv[4] = f2bf(kb.x); kv[5] = f2bf(kb.y); kv[6] = f2bf(kb.z); kv[7] = f2bf(kb.w);
            *(short8*)&kt[sn * 72 + sdc * 8] = kv;
            const float m = mask[b * NN + n0 + sub * 32 + sn];
            const float4 va = *(const float4*)(Vmat + off);
            const float4 vb = *(const float4*)(Vmat + off + 4);
            short8 vv;
            vv[0] = f2bf(va.x * m); vv[1] = f2bf(va.y * m);
            vv[2] = f2bf(va.z * m); vv[3] = f2bf(va.w * m);
            vv[4] = f2bf(vb.x * m); vv[5] = f2bf(vb.y * m);
            vv[6] = f2bf(vb.z * m); vv[7] = f2bf(vb.w * m);
            *(short8*)&vrm[sn * 72 + sdc * 8] = vv;
            if (tid < 32) mlds[tid] = mask[b * NN + n0 + sub * 32 + tid];
        }
        __syncthreads();
        // ---- gather-transpose V: vt[d][n] ----
        {
            const int d = tid & 63, nc = tid >> 6;
            short8 g;
#pragma unroll
            for (int j = 0; j < 8; ++j) g[j] = vrm[(nc * 8 + j) * 72 + d];
            *(short8*)&vt[d * 40 + nc * 8] = g;
        }
        // epilogue row masks
        float mrow[16];
#pragma unroll
        for (int i = 0; i < 16; ++i)
            mrow[i] = mlds[(i & 3) + 8 * (i >> 2) + 4 * hf];
        // ---- GEMM1: phi tile (A = K, B = proj-frags) ----
        short8 afr[4];
#pragma unroll
        for (int ks = 0; ks < 4; ++ks)
            afr[ks] = *(const short8*)&kt[l31 * 72 + ks * 16 + hf * 8];
#pragma unroll
        for (int rt = 0; rt < 2; ++rt) {
            f32x16 p = fzero16();
#pragma unroll
            for (int ks = 0; ks < 4; ++ks)
                p = MFMA(afr[ks], pfrag[rt][ks], p);
            const int r = wave * 64 + rt * 32 + l31;
            float phiv[16];
#pragma unroll
            for (int i = 0; i < 16; ++i) {
                const float ph = fmaxf(p[i] * SCALE * mrow[i], 0.f) + KEPS;
                phiv[i] = ph;
                ksum_acc[rt] += ph;
            }
#pragma unroll
            for (int g4 = 0; g4 < 4; ++g4) {   // rows 8*g4+4*hf+{0..3}
                short4v w;
                w[0] = f2bf(phiv[4 * g4 + 0]); w[1] = f2bf(phiv[4 * g4 + 1]);
                w[2] = f2bf(phiv[4 * g4 + 2]); w[3] = f2bf(phiv[4 * g4 + 3]);
                *(short4v*)&phiT[r * 40 + 8 * g4 + 4 * hf] = w;
            }
        }
        __syncthreads();   // vt visible to all waves
        // ---- GEMM2: ctx += phi^T . V (A = phiT, B = vt) ----
#pragma unroll
        for (int ks2 = 0; ks2 < 2; ++ks2) {
            const short8 a0 = *(const short8*)&phiT[(wave * 64 + l31) * 40 + ks2 * 16 + hf * 8];
            const short8 a1 = *(const short8*)&phiT[(wave * 64 + 32 + l31) * 40 + ks2 * 16 + hf * 8];
            const short8 b0 = *(const short8*)&vt[l31 * 40 + ks2 * 16 + hf * 8];
            const short8 b1 = *(const short8*)&vt[(32 + l31) * 40 + ks2 * 16 + hf * 8];
            cacc[0][0] = MFMA(a0, b0, cacc[0][0]);
            cacc[0][1] = MFMA(a0, b1, cacc[0][1]);
            cacc[1][0] = MFMA(a1, b0, cacc[1][0]);
            cacc[1][1] = MFMA(a1, b1, cacc[1][1]);
        }
    }
    // ---- epilogue: coalesced fp32 atomics ----
#pragma unroll
    for (int rt = 0; rt < 2; ++rt)
#pragma unroll
        for (int dt = 0; dt < 2; ++dt)
#pragma unroll
            for (int i = 0; i < 16; ++i) {
                const int row = (i & 3) + 8 * (i >> 2) + 4 * hf;
                atomicAdd(g_ctx + ((long)bh * RR + wave * 64 + rt * 32 + row) * DD
                                + dt * 32 + l31, cacc[rt][dt][i]);
            }
#pragma unroll
    for (int rt = 0; rt < 2; ++rt) {
        float ks = ksum_acc[rt];
        ks += __shfl_xor(ks, 32, 64);
        if (hf == 0)
            atomicAdd(g_ksum + bh * RR + wave * 64 + rt * 32 + l31, ks);
    }
}

// ---------------------------------------------------------------------------
// Kernel 2: per (bh, n-chunk of 64):
//   phi_q^T[r][n] = relu(scale*(proj.Q^T)) + eps   (MFMA, C: m=r col=n)
//   s[n] = phi_q . ksum                            (VALU matvec from LDS)
//   out[n][d] = (phi_q . ctx) / s[n]               (MFMA, C: m=n col=d, k=r=256)
// phiq LDS [n][r-fastest] xor-chunk-swizzled; ctx^T LDS [d][r-fastest] same.
// ---------------------------------------------------------------------------
__global__ __launch_bounds__(256, 2)
void out_kernel(const float* __restrict__ Qmat, const float* __restrict__ proj,
                const float* __restrict__ g_ctx, const float* __restrict__ g_ksum,
                float* __restrict__ out)
{
    __shared__ __align__(16) short qt[64 * 72];     // Q [n][d] pad 72
    __shared__ __align__(16) short phiq[64 * 256];  // [n][r] chunk^=(n&31)
    __shared__ __align__(16) short ct[64 * 256];    // [d][r] chunk^=(d&31)
    __shared__ float ks_lds[256];
    __shared__ float s_lds[64];

    const int tid  = threadIdx.x;
    const int wave = tid >> 6, lane = tid & 63;
    const int l31  = lane & 31, hf = lane >> 5;
    const int b = blockIdx.z, h = blockIdx.y;
    const int bh = b * HH + h;
    const int n0 = blockIdx.x * 64;

    // resident proj A-frags (identical lane data to kernel-1 B-frags)
    short8 pfrag[2][4];
#pragma unroll
    for (int rt = 0; rt < 2; ++rt)
#pragma unroll
        for (int ks = 0; ks < 4; ++ks) {
            const int r  = wave * 64 + rt * 32 + l31;
            const int d0 = ks * 16 + hf * 8;
            const float4 a = *(const float4*)(proj + r * DD + d0);
            const float4 c = *(const float4*)(proj + r * DD + d0 + 4);
            short8 v;
            v[0] = f2bf(a.x); v[1] = f2bf(a.y); v[2] = f2bf(a.z); v[3] = f2bf(a.w);
            v[4] = f2bf(c.x); v[5] = f2bf(c.y); v[6] = f2bf(c.z); v[7] = f2bf(c.w);
            pfrag[rt][ks] = v;
        }

    // ---- stage Q (64 rows), ksum, ctx^T ----
#pragma unroll
    for (int p = 0; p < 2; ++p) {
        const int i = tid + p * 256;
        const int n = i >> 3, dc = i & 7;
        const long off = ((long)bh * NN + n0 + n) * DD + dc * 8;
        const float4 a = *(const float4*)(Qmat + off);
        const float4 c = *(const float4*)(Qmat + off + 4);
        short8 v;
        v[0] = f2bf(a.x); v[1] = f2bf(a.y); v[2] = f2bf(a.z); v[3] = f2bf(a.w);
        v[4] = f2bf(c.x); v[5] = f2bf(c.y); v[6] = f2bf(c.z); v[7] = f2bf(c.w);
        *(short8*)&qt[n * 72 + dc * 8] = v;
    }
    ks_lds[tid] = g_ksum[bh * RR + tid];
    {
        const int d = tid & 63, rc0 = tid >> 6;
#pragma unroll
        for (int i = 0; i < 8; ++i) {
            const int rc = rc0 * 8 + i;
            short8 v;
#pragma unroll
            for (int j = 0; j < 8; ++j)
                v[j] = f2bf(g_ctx[((long)bh * RR + rc * 8 + j) * DD + d]);
            *(short8*)&ct[d * 256 + (rc ^ (d & 31)) * 8] = v;
        }
    }
    __syncthreads();

    // ---- GEMM3: phi_q^T (A = proj-frags, B = Q) ----
    for (int sub = 0; sub < 2; ++sub) {
        short8 qfr[4];
#pragma unroll
        for (int ks = 0; ks < 4; ++ks)
            qfr[ks] = *(const short8*)&qt[(sub * 32 + l31) * 72 + ks * 16 + hf * 8];
        const int n = sub * 32 + l31;   // C col = n
#pragma unroll
        for (int rt = 0; rt < 2; ++rt) {
            f32x16 p = fzero16();
#pragma unroll
            for (int ks = 0; ks < 4; ++ks)
                p = MFMA(pfrag[rt][ks], qfr[ks], p);
#pragma unroll
            for (int g4 = 0; g4 < 4; ++g4) {   // rows r0..r0+3
                const int r0 = wave * 64 + rt * 32 + 8 * g4 + 4 * hf;
                short4v w;
                w[0] = f2bf(fmaxf(p[4 * g4 + 0] * SCALE, 0.f) + KEPS);
                w[1] = f2bf(fmaxf(p[4 * g4 + 1] * SCALE, 0.f) + KEPS);
                w[2] = f2bf(fmaxf(p[4 * g4 + 2] * SCALE, 0.f) + KEPS);
                w[3] = f2bf(fmaxf(p[4 * g4 + 3] * SCALE, 0.f) + KEPS);
                *(short4v*)&phiq[n * 256 + ((r0 >> 3) ^ (n & 31)) * 8 + (r0 & 7)] = w;
            }
        }
    }
    __syncthreads();

    // ---- s[n] = phi_q . ksum ----
    {
        const int n = tid >> 2, rq = tid & 3;
        float s = 0.f;
#pragma unroll
        for (int c = rq * 8; c < rq * 8 + 8; ++c) {
            const short8 v = *(const short8*)&phiq[n * 256 + (c ^ (n & 31)) * 8];
            const float4 ka = *(const float4*)&ks_lds[c * 8];
            const float4 kb = *(const float4*)&ks_lds[c * 8 + 4];
            s = fmaf(bf2f(v[0]), ka.x, s); s = fmaf(bf2f(v[1]), ka.y, s);
            s = fmaf(bf2f(v[2]), ka.z, s); s = fmaf(bf2f(v[3]), ka.w, s);
            s = fmaf(bf2f(v[4]), kb.x, s); s = fmaf(bf2f(v[5]), kb.y, s);
            s = fmaf(bf2f(v[6]), kb.z, s); s = fmaf(bf2f(v[7]), kb.w, s);
        }
        s += __shfl_xor(s, 1, 64);
        s += __shfl_xor(s, 2, 64);
        if (rq == 0) s_lds[n] = s;
    }
    __syncthreads();

    // ---- GEMM4: out = phi_q . ctx / s   (k = r = 256 -> 16 ksteps) ----
    {
        const int ns = wave >> 1, dt = wave & 1;
        const int na = ns * 32 + l31;    // A m-index (n-local)
        const int dcol = dt * 32 + l31;  // B col (d)
        f32x16 acc = fzero16();
#pragma unroll
        for (int ks = 0; ks < 16; ++ks) {
            const int c = 2 * ks + hf;
            const short8 a = *(const short8*)&phiq[na * 256 + (c ^ (na & 31)) * 8];
            const short8 bf = *(const short8*)&ct[dcol * 256 + (c ^ (dcol & 31)) * 8];
            acc = MFMA(a, bf, acc);
        }
#pragma unroll
        for (int i = 0; i < 16; ++i) {
            const int row = (i & 3) + 8 * (i >> 2) + 4 * hf;   // n-local in slice
            const float sinv = 1.0f / s_lds[ns * 32 + row];
            out[((long)bh * NN + n0 + ns * 32 + row) * DD + dcol] = acc[i] * sinv;
        }
    }
}

// ---------------------------------------------------------------------------
extern "C" void kernel_launch(void* const* d_in, const int* in_sizes, int n_in,
                              void* d_out, int out_size, void* d_ws, size_t ws_size,
                              hipStream_t stream)
{
    const float* Q    = (const float*)d_in[0];
    const float* K    = (const float*)d_in[1];
    const float* V    = (const float*)d_in[2];
    const float* mask = (const float*)d_in[3];
    const float* proj = (const float*)d_in[4];
    float* out = (float*)d_out;

    float* g_ctx  = (float*)d_ws;                        // BH*RR*DD fp32 (2 MB)
    float* g_ksum = g_ctx + (size_t)BB * HH * RR * DD;   // BH*RR fp32
    const size_t zbytes = ((size_t)BB * HH * RR * DD + (size_t)BB * HH * RR) * sizeof(float);
    hipMemsetAsync(d_ws, 0, zbytes, stream);

    dim3 g1(NN / NT1, HH, BB);   // (16, 8, 4) = 512 blocks
    pk_ctx_kernel<<<g1, 256, 0, stream>>>(K, V, mask, proj, g_ctx, g_ksum);

    dim3 g2(NN / 64, HH, BB);    // (64, 8, 4) = 2048 blocks
    out_kernel<<<g2, 256, 0, stream>>>(Q, proj, g_ctx, g_ksum, out);
}